// Round 12
// baseline (88.463 us; speedup 1.0000x reference)
//
#include <hip/hip_runtime.h>
#include <hip/hip_fp8.h>

typedef float  float4_t __attribute__((ext_vector_type(4)));
typedef unsigned int uint2_t __attribute__((ext_vector_type(2)));
typedef float  f32x4   __attribute__((ext_vector_type(4)));
typedef int    int4_t  __attribute__((ext_vector_type(4)));

#define FEAT   256
#define BANK   2048
#define NROWS  2048       // 256 anchors * 8 views
#define NPAN   576        // 64-col panels over 36864 cols
#define NSTRIP 64         // 32-row strips
#define INV_TEMP 10.0f
#define EXP2K  14.4269504088896f   // 10 * log2(e): exp(10x) = 2^(x*EXP2K)
#define A_CH8  65536      // A 8-byte chunks: 64 strips * 2 mi * 8 ks * 64 lanes
#define B_CH8  1179648    // B 8-byte chunks: 576 panels * 32 frags * 64 lanes
#define TOT8   (A_CH8 + B_CH8)

__device__ inline unsigned char to_fp8(float x) {
    __hip_fp8_e4m3 f(x);
    return *reinterpret_cast<unsigned char*>(&f);
}

// 16-lane (DPP row) sum: every lane of each 16-lane group gets the group total.
__device__ inline float rowsum16(float x) {
    float t;
    asm("s_nop 1\n\tv_add_f32 %0, %1, %1 row_ror:1"  : "=v"(t) : "v"(x)); x = t;
    asm("s_nop 1\n\tv_add_f32 %0, %1, %1 row_ror:2"  : "=v"(t) : "v"(x)); x = t;
    asm("s_nop 1\n\tv_add_f32 %0, %1, %1 row_ror:4"  : "=v"(t) : "v"(x)); x = t;
    asm("s_nop 1\n\tv_add_f32 %0, %1, %1 row_ror:8"  : "=v"(t) : "v"(x)); x = t;
    return x;
}

// Pass 0: fp32 -> fp8 e4m3 ONCE, packed in MFMA fragment order.
// A: strip s (32 rows), frag (mi,ks): lane l byte i -> row s*32+mi*16+(l&15),
//    k = ks*32+(l>>4)*8+i.  cid = s*1024 + mi*512 + ks*64 + lane.
// B: panel p (64 cols), frag (ni,ks): lane l byte i -> col p*64+ni*16+(l&15).
__global__ __launch_bounds__(256) void pass0_pack(
    const float* __restrict__ X,    // X_anchor [256][8][256]
    const float* __restrict__ Q,    // queue [19][2048][256]
    unsigned char* __restrict__ Abuf,
    unsigned char* __restrict__ Bbuf,
    float* __restrict__ out)
{
    const int cid = blockIdx.x * 256 + threadIdx.x;
    if (cid == 0) out[0] = 0.0f;
    if (cid >= TOT8) return;
    const int lane = cid & 63;
    const int ks   = (cid >> 6) & 7;
    const int k    = ks * 32 + ((lane >> 4) << 3);
    const float* src;
    unsigned char* dst;
    if (cid < A_CH8) {
        const int mi = (cid >> 9) & 1, s = cid >> 10;
        const int r  = s * 32 + mi * 16 + (lane & 15);      // anchor row = v*256+a
        src = X + ((size_t)((r & 255) * 8 + (r >> 8))) * FEAT + k;
        dst = Abuf + ((size_t)cid << 3);
    } else {
        const int b = cid - A_CH8;
        const int ni = (b >> 9) & 3, p = b >> 11;
        const int col = p * 64 + ni * 16 + (lane & 15);     // class 0 skipped
        src = Q + ((size_t)(BANK + col)) * FEAT + k;
        dst = Bbuf + ((size_t)b << 3);
    }
    float4_t v0 = *(const float4_t*)src;
    float4_t v1 = *(const float4_t*)(src + 4);
    const unsigned int b0 = to_fp8(v0.x) | ((unsigned int)to_fp8(v0.y) << 8)
                          | ((unsigned int)to_fp8(v0.z) << 16) | ((unsigned int)to_fp8(v0.w) << 24);
    const unsigned int b1 = to_fp8(v1.x) | ((unsigned int)to_fp8(v1.y) << 8)
                          | ((unsigned int)to_fp8(v1.z) << 16) | ((unsigned int)to_fp8(v1.w) << 24);
    uint2_t u = { b0, b1 };
    *(uint2_t*)dst = u;
}

// Pass 1: BARRIER-FREE streaming, low-VGPR for residency. No LDS. Each wave:
// A-frags (32 rows x K=256 fp8 = 32 VGPR) pinned; 3 private 64-col panels,
// B streamed global->regs, 64 fp8 MFMA/panel, exp2 epilogue + DPP row-reduce.
// ~150 total regs -> 3 waves/SIMD (12 waves/CU).
__global__ __launch_bounds__(256, 3) void pass1_gemm(
    const unsigned char* __restrict__ Abuf,
    const unsigned char* __restrict__ Bbuf,
    const int*   __restrict__ y,
    float* __restrict__ partS,  // [NROWS][NPAN]
    float* __restrict__ partL,  // [NROWS][NPAN] (sparse: pos panels, acc units x10)
    float* __restrict__ diagL)  // [NROWS]
{
    // XCD-banded: xcd owns panels [xcd*72, xcd*72+72)
    const int bid   = blockIdx.x;
    const int xcd   = bid & 7;
    const int j     = bid >> 3;            // 0..383
    const int strip = j & 63;              // 32-row strip
    const int pg    = xcd * 6 + (j >> 6);  // 0..47 (12 panels each)

    const int t = threadIdx.x, lane = t & 63, w = t >> 6;
    const int g = lane >> 4, ci = lane & 15;

    // ---- A fragments in registers (32 rows x 256 K fp8 = 32 VGPR) ----
    const long* Ap = (const long*)(Abuf + ((size_t)strip << 13));
    long a[2][8];
    #pragma unroll
    for (int mi = 0; mi < 2; ++mi)
        #pragma unroll
        for (int ks = 0; ks < 8; ++ks)
            a[mi][ks] = Ap[((mi << 3) | ks) * 64 + lane];

    // ---- per-lane row classes ----
    int4_t yv[2];
    #pragma unroll
    for (int mi = 0; mi < 2; ++mi)
        yv[mi] = *(const int4_t*)(y + ((strip * 32 + mi * 16 + g * 4) & 255));

    const int pd = strip >> 1;                     // panel containing diag cols
    const int dsub = (strip & 1) * 32;             // col offset of row 0 in pd

    #pragma unroll 1
    for (int pi = 0; pi < 3; ++pi) {
        const int p  = pg * 12 + w * 3 + pi;
        const int cj = (p >> 5) + 1;               // class of this panel (1..18)
        const long* Bp = (const long*)(Bbuf + ((size_t)p << 14));

        long b[4][8];
        #pragma unroll
        for (int ni = 0; ni < 4; ++ni)
            #pragma unroll
            for (int ks = 0; ks < 8; ++ks)
                b[ni][ks] = Bp[((ni << 3) | ks) * 64 + lane];

        f32x4 acc[2][4] = {};
        #pragma unroll
        for (int ni = 0; ni < 4; ++ni)
            #pragma unroll
            for (int ks = 0; ks < 8; ++ks) {
                acc[0][ni] = __builtin_amdgcn_mfma_f32_16x16x32_fp8_fp8(
                    a[0][ks], b[ni][ks], acc[0][ni], 0, 0, 0);
                acc[1][ni] = __builtin_amdgcn_mfma_f32_16x16x32_fp8_fp8(
                    a[1][ks], b[ni][ks], acc[1][ni], 0, 0, 0);
            }

        // ---- epilogue: per-row exp2-sum + pos acc-sum, DPP reduce, store ----
        #pragma unroll
        for (int mi = 0; mi < 2; ++mi) {
            #pragma unroll
            for (int rj = 0; rj < 4; ++rj) {
                const int r = strip * 32 + mi * 16 + g * 4 + rj;
                const bool isPos = (yv[mi][rj] == cj);
                float rs = 0.0f, lp = 0.0f;
                #pragma unroll
                for (int ni = 0; ni < 4; ++ni) {
                    const float av = acc[mi][ni][rj];
                    rs += __builtin_exp2f(av * EXP2K);
                    if (isPos) lp += av;
                    if (p == pd && (ni * 16 + ci) == (dsub + mi * 16 + g * 4 + rj))
                        diagL[r] = av * INV_TEMP;
                }
                rs = rowsum16(rs);
                lp = rowsum16(lp);
                if (ci == 0) {
                    partS[(size_t)r * NPAN + p] = rs;
                    if (isPos) partL[(size_t)r * NPAN + p] = lp * INV_TEMP;
                }
            }
        }
    }
}

// Pass 3: per-row finish. S = sum_p partS[r][p]; E1 over the 32 pos panels;
// neg = S - E1 + 2048; loss_r = ln(neg) - Lp'/m (m=2047 & diag removed for c==1).
__global__ __launch_bounds__(256) void pass3_kernel(
    const int* __restrict__ y,
    const float* __restrict__ partS, const float* __restrict__ partL,
    const float* __restrict__ diagL, float* __restrict__ out)
{
    __shared__ float sh[4];
    const int r = blockIdx.x * 256 + threadIdx.x;
    const int c = y[r & 255];

    const float4_t* ps = (const float4_t*)(partS + (size_t)r * NPAN);
    float S = 0.0f, E1 = 0.0f;
    const int b4 = (c - 1) * 8;                // pos band start in float4 units
    #pragma unroll 4
    for (int q = 0; q < NPAN / 4; ++q) {
        const float4_t v = ps[q];
        const float ss = v.x + v.y + v.z + v.w;
        S += ss;
        if (q >= b4 && q < b4 + 8) E1 += ss;
    }
    float Lp = 0.0f;
    const float4_t* pl = (const float4_t*)(partL + (size_t)r * NPAN + (c - 1) * 32);
    #pragma unroll
    for (int q = 0; q < 8; ++q) {
        const float4_t v = pl[q];
        Lp += v.x + v.y + v.z + v.w;
    }
    float m = 2048.0f;
    if (c == 1) { Lp -= diagL[r]; m = 2047.0f; }
    const float neg = S - E1 + 2048.0f;
    float lr = __logf(neg) - Lp / m;

    #pragma unroll
    for (int mm = 1; mm < 64; mm <<= 1) lr += __shfl_xor(lr, mm);
    const int w = threadIdx.x >> 6;
    if ((threadIdx.x & 63) == 0) sh[w] = lr;
    __syncthreads();
    if (threadIdx.x == 0)
        atomicAdd(out, (sh[0] + sh[1] + sh[2] + sh[3]) * (1.0f / (float)NROWS));
}

extern "C" void kernel_launch(void* const* d_in, const int* in_sizes, int n_in,
                              void* d_out, int out_size, void* d_ws, size_t ws_size,
                              hipStream_t stream) {
    const float* X = (const float*)d_in[0];
    const int*   y = (const int*)d_in[1];
    const float* Q = (const float*)d_in[2];
    float* out   = (float*)d_out;
    float* partS = (float*)d_ws;                                // 2048*576 f32 (4.72 MB)
    float* partL = partS + (size_t)NROWS * NPAN;                // 4.72 MB
    float* diagL = partL + (size_t)NROWS * NPAN;                // 8 KB
    unsigned char* Abuf = (unsigned char*)(diagL + NROWS);      // 512 KB
    unsigned char* Bbuf = Abuf + ((size_t)A_CH8 << 3);          // 9.44 MB

    pass0_pack<<<dim3(TOT8 / 256), dim3(256), 0, stream>>>(X, Q, Abuf, Bbuf, out);
    pass1_gemm<<<dim3(64 * 48), dim3(256), 0, stream>>>(Abuf, Bbuf, y, partS, partL, diagL);
    pass3_kernel<<<dim3(NROWS / 256), dim3(256), 0, stream>>>(y, partS, partL, diagL, out);
}